// Round 1
// baseline (337.893 us; speedup 1.0000x reference)
//
#include <hip/hip_runtime.h>

#define IN_F   1024
#define OUT_F  1024
#define BATCHN 4096
#define KDIM   9216   // 9 * 1024 (t-plane layout: k = t*1024 + i)

using bf16x8 = __attribute__((ext_vector_type(8))) __bf16;
using f32x4  = __attribute__((ext_vector_type(4))) float;

__device__ __forceinline__ unsigned short f2bf(float f) {
  union { float f; unsigned int u; } v; v.f = f;
  unsigned int u = v.u;
  unsigned int r = (u + 0x7FFFu + ((u >> 16) & 1u)) >> 16;  // RNE
  return (unsigned short)r;
}

__device__ __forceinline__ void async_load16(const void* g, void* l) {
  __builtin_amdgcn_global_load_lds(
      (__attribute__((address_space(1))) void*)(g),
      (__attribute__((address_space(3))) void*)(l),
      16, 0, 0);
}

// ---------------------------------------------------------------------------
// Ã[b][t*1024+i] : t=0 -> silu(x[b,i]); t=1..8 -> cubic B-spline basis values
// ---------------------------------------------------------------------------
__global__ __launch_bounds__(256) void kan_prep_a(const float* __restrict__ x,
                                                  const float* __restrict__ grid,
                                                  unsigned short* __restrict__ A) {
  int idx = blockIdx.x * 256 + threadIdx.x;      // b*1024 + i, i fastest
  int i = idx & 1023;
  float xv = x[idx];
  float sil = xv / (1.0f + __expf(-xv));

  const float* g = grid + i * 12;
  float t[12];
#pragma unroll
  for (int j = 0; j < 12; ++j) t[j] = g[j];

  float B[11];
#pragma unroll
  for (int j = 0; j < 11; ++j) B[j] = (xv >= t[j] && xv < t[j + 1]) ? 1.0f : 0.0f;
#pragma unroll
  for (int p = 1; p <= 3; ++p) {
#pragma unroll
    for (int j = 0; j + p < 11; ++j) {
      float left  = (xv - t[j]) / (t[j + p] - t[j]);
      float right = (t[j + p + 1] - xv) / (t[j + p + 1] - t[j + 1]);
      B[j] = left * B[j] + right * B[j + 1];
    }
  }

  size_t base = (size_t)(idx >> 10) * KDIM + i;
  A[base] = f2bf(sil);                            // t = 0 plane
#pragma unroll
  for (int k = 0; k < 8; ++k) A[base + (size_t)(k + 1) * 1024] = f2bf(B[k]);
}

// ---------------------------------------------------------------------------
// W_T[o][t*1024+i] = t==0 ? scale_base[i,o] : scale_sp[i,o]*coef[i,o,t-1]
// (pre-transposed so GEMM B-fragments are contiguous along K)
// ---------------------------------------------------------------------------
__global__ __launch_bounds__(256) void kan_prep_w(const float* __restrict__ sb,
                                                  const float* __restrict__ ssp,
                                                  const float* __restrict__ coef,
                                                  unsigned short* __restrict__ WT) {
  __shared__ unsigned short lds[9][32][33];
  int i0 = (blockIdx.x >> 5) * 32, o0 = (blockIdx.x & 31) * 32;
  int tid = threadIdx.x;
#pragma unroll
  for (int r = 0; r < 4; ++r) {
    int idx = r * 256 + tid;
    int ii = idx >> 5, oo = idx & 31;
    int io = (i0 + ii) * 1024 + (o0 + oo);
    float b = sb[io], s = ssp[io];
    const float4* cp = (const float4*)(coef + (size_t)io * 8);
    float4 c0 = cp[0], c1 = cp[1];
    lds[0][ii][oo] = f2bf(b);
    lds[1][ii][oo] = f2bf(s * c0.x);
    lds[2][ii][oo] = f2bf(s * c0.y);
    lds[3][ii][oo] = f2bf(s * c0.z);
    lds[4][ii][oo] = f2bf(s * c0.w);
    lds[5][ii][oo] = f2bf(s * c1.x);
    lds[6][ii][oo] = f2bf(s * c1.y);
    lds[7][ii][oo] = f2bf(s * c1.z);
    lds[8][ii][oo] = f2bf(s * c1.w);
  }
  __syncthreads();
#pragma unroll
  for (int r = 0; r < 4; ++r) {
    int idx = r * 256 + tid;
    int oo = idx >> 5, ii = idx & 31;
    size_t rowbase = (size_t)(o0 + oo) * KDIM + i0 + ii;
#pragma unroll
    for (int tp = 0; tp < 9; ++tp) WT[rowbase + tp * 1024] = lds[tp][ii][oo];
  }
}

// ---------------------------------------------------------------------------
// GEMM: C[4096][1024] = Ã[4096][9216] * W (B given as W_T, row-major N x K)
// 128x128 tile, BK=64, 8 waves (2x4), double-buffered LDS, global_load_lds.
// ---------------------------------------------------------------------------
#define BM 128
#define BN 128
#define BK 64

__global__ __launch_bounds__(512) void kan_gemm(const unsigned short* __restrict__ A,
                                                const unsigned short* __restrict__ BT,
                                                float* __restrict__ C) {
  __shared__ unsigned short As[2][BM * BK];
  __shared__ unsigned short Bs[2][BN * BK];
  const int tid = threadIdx.x;
  const int wid = tid >> 6, lane = tid & 63;
  const int wr = wid >> 2, wc = wid & 3;        // 2 x 4 wave grid -> 64x32 per wave
  const int row16 = lane & 15, kgrp = lane >> 4;
  const int bmi = blockIdx.x >> 3, bni = blockIdx.x & 7;
  const int m0 = bmi * BM, n0 = bni * BN;
  const size_t ldb = (size_t)KDIM * 2;          // row stride in bytes (both A and BT)

  const char* Ab = (const char*)A;
  const char* Bb = (const char*)BT;

  f32x4 acc[4][2] = {};

  auto stage = [&](int buf, int kt) {
    size_t kbyte = (size_t)kt * (BK * 2);
#pragma unroll
    for (int q = 0; q < 2; ++q) {
      int d = q * 8192 + tid * 16;              // byte offset within 16 KiB tile
      int row = d >> 7, colb = d & 127;         // 128 B per tile row (64 bf16)
      unsigned ldsoff = q * 8192 + wid * 1024;  // wave-uniform dest base
      async_load16(Ab + (size_t)(m0 + row) * ldb + kbyte + colb,
                   (char*)(&As[buf][0]) + ldsoff);
      async_load16(Bb + (size_t)(n0 + row) * ldb + kbyte + colb,
                   (char*)(&Bs[buf][0]) + ldsoff);
    }
  };

  stage(0, 0);
  __syncthreads();

  const int NT = KDIM / BK;                     // 144
  for (int kt = 0; kt < NT; ++kt) {
    int cur = kt & 1;
    if (kt + 1 < NT) stage(cur ^ 1, kt + 1);    // prefetch next tile (async)
    const unsigned short* as = &As[cur][0];
    const unsigned short* bs = &Bs[cur][0];
#pragma unroll
    for (int ks = 0; ks < 2; ++ks) {
      bf16x8 af[4], bfr[2];
#pragma unroll
      for (int m = 0; m < 4; ++m)
        af[m] = *(const bf16x8*)(as + (wr * 64 + m * 16 + row16) * BK + ks * 32 + kgrp * 8);
#pragma unroll
      for (int n = 0; n < 2; ++n)
        bfr[n] = *(const bf16x8*)(bs + (wc * 32 + n * 16 + row16) * BK + ks * 32 + kgrp * 8);
#pragma unroll
      for (int m = 0; m < 4; ++m)
#pragma unroll
        for (int n = 0; n < 2; ++n)
          acc[m][n] = __builtin_amdgcn_mfma_f32_16x16x32_bf16(af[m], bfr[n], acc[m][n], 0, 0, 0);
    }
    __syncthreads();                            // drains prefetch vmcnt + reuse gate
  }

  float* Cb = C + (size_t)(m0 + wr * 64) * OUT_F + n0 + wc * 32;
#pragma unroll
  for (int m = 0; m < 4; ++m)
#pragma unroll
    for (int n = 0; n < 2; ++n)
#pragma unroll
      for (int r = 0; r < 4; ++r) {
        int row = m * 16 + kgrp * 4 + r;        // C/D: row=(lane>>4)*4+reg
        int col = n * 16 + row16;               //      col=lane&15
        Cb[(size_t)row * OUT_F + col] = acc[m][n][r];
      }
}

// ---------------------------------------------------------------------------
// In-place LayerNorm over last dim (1024), one block per row.
// ---------------------------------------------------------------------------
__global__ __launch_bounds__(256) void kan_ln(float* __restrict__ y,
                                              const float* __restrict__ gamma,
                                              const float* __restrict__ beta) {
  __shared__ float ss[4], ssq[4];
  int tid = threadIdx.x;
  float4* p = (float4*)(y + (size_t)blockIdx.x * OUT_F);
  float4 v = p[tid];
  float s = v.x + v.y + v.z + v.w;
  float q = v.x * v.x + v.y * v.y + v.z * v.z + v.w * v.w;
#pragma unroll
  for (int off = 1; off < 64; off <<= 1) {
    s += __shfl_xor(s, off);
    q += __shfl_xor(q, off);
  }
  if ((tid & 63) == 0) { ss[tid >> 6] = s; ssq[tid >> 6] = q; }
  __syncthreads();
  float S = ss[0] + ss[1] + ss[2] + ss[3];
  float Q = ssq[0] + ssq[1] + ssq[2] + ssq[3];
  float mu  = S * (1.0f / OUT_F);
  float var = Q * (1.0f / OUT_F) - mu * mu;
  float inv = rsqrtf(var + 1e-5f);
  const float4 g  = ((const float4*)gamma)[tid];
  const float4 bt = ((const float4*)beta)[tid];
  float4 o;
  o.x = (v.x - mu) * inv * g.x + bt.x;
  o.y = (v.y - mu) * inv * g.y + bt.y;
  o.z = (v.z - mu) * inv * g.z + bt.z;
  o.w = (v.w - mu) * inv * g.w + bt.w;
  p[tid] = o;
}

extern "C" void kernel_launch(void* const* d_in, const int* in_sizes, int n_in,
                              void* d_out, int out_size, void* d_ws, size_t ws_size,
                              hipStream_t stream) {
  const float* x     = (const float*)d_in[0];
  const float* coef  = (const float*)d_in[1];
  const float* sb    = (const float*)d_in[2];
  const float* ssp   = (const float*)d_in[3];
  const float* gamma = (const float*)d_in[4];
  const float* beta  = (const float*)d_in[5];
  const float* grid  = (const float*)d_in[6];

  const size_t a_elems  = (size_t)BATCHN * KDIM;   // 37.75M bf16 = 75.5 MB
  const size_t wt_elems = (size_t)OUT_F * KDIM;    // 9.4M bf16  = 18.9 MB
  if (ws_size < (a_elems + wt_elems) * sizeof(unsigned short)) return;  // clean fail

  unsigned short* A  = (unsigned short*)d_ws;
  unsigned short* WT = A + a_elems;
  float* y = (float*)d_out;

  kan_prep_a<<<dim3((BATCHN * IN_F) / 256), dim3(256), 0, stream>>>(x, grid, A);
  kan_prep_w<<<dim3((IN_F / 32) * (OUT_F / 32)), dim3(256), 0, stream>>>(sb, ssp, coef, WT);
  kan_gemm<<<dim3((BATCHN / BM) * (OUT_F / BN)), dim3(512), 0, stream>>>(A, WT, y);
  kan_ln<<<dim3(BATCHN), dim3(256), 0, stream>>>(y, gamma, beta);
}

// Round 2
// 172.276 us; speedup vs baseline: 1.9613x; 1.9613x over previous
//
#include <hip/hip_runtime.h>

#define IN_F   1024
#define OUT_F  1024
#define BATCHN 4096
#define KDIM   9216   // 9 * 1024 (t-plane layout: k = t*1024 + i)

using bf16x8 = __attribute__((ext_vector_type(8))) __bf16;
using f32x4  = __attribute__((ext_vector_type(4))) float;

__device__ __forceinline__ unsigned short f2bf(float f) {
  union { float f; unsigned int u; } v; v.f = f;
  unsigned int u = v.u;
  unsigned int r = (u + 0x7FFFu + ((u >> 16) & 1u)) >> 16;  // RNE
  return (unsigned short)r;
}

__device__ __forceinline__ void async_load16(const void* g, void* l) {
  __builtin_amdgcn_global_load_lds(
      (__attribute__((address_space(1))) void*)(g),
      (__attribute__((address_space(3))) void*)(l),
      16, 0, 0);
}

// ---------------------------------------------------------------------------
// Ã[b][t*1024+i] : t=0 -> silu(x[b,i]); t=1..8 -> cubic B-spline basis values
// Uniform knots -> denominators are p*h: one rcp + multiplies (no v_div chains)
// ---------------------------------------------------------------------------
__global__ __launch_bounds__(256) void kan_prep_a(const float* __restrict__ x,
                                                  const float* __restrict__ grid,
                                                  unsigned short* __restrict__ A) {
  int idx = blockIdx.x * 256 + threadIdx.x;      // b*1024 + i, i fastest
  int i = idx & 1023;
  float xv = x[idx];
  float sil = xv / (1.0f + __expf(-xv));

  const float* g = grid + i * 12;
  float t[12];
#pragma unroll
  for (int j = 0; j < 12; ++j) t[j] = g[j];

  float B[11];
#pragma unroll
  for (int j = 0; j < 11; ++j) B[j] = (xv >= t[j] && xv < t[j + 1]) ? 1.0f : 0.0f;

  float inv_h = 1.0f / (t[4] - t[3]);            // uniform spacing
  const float invp[3] = {inv_h, inv_h * 0.5f, inv_h * (1.0f / 3.0f)};
#pragma unroll
  for (int p = 1; p <= 3; ++p) {
    float ip = invp[p - 1];
#pragma unroll
    for (int j = 0; j + p < 11; ++j)
      B[j] = (xv - t[j]) * ip * B[j] + (t[j + p + 1] - xv) * ip * B[j + 1];
  }

  size_t base = (size_t)(idx >> 10) * KDIM + i;
  A[base] = f2bf(sil);                            // t = 0 plane
#pragma unroll
  for (int k = 0; k < 8; ++k) A[base + (size_t)(k + 1) * 1024] = f2bf(B[k]);
}

// ---------------------------------------------------------------------------
// W_T[o][t*1024+i] = t==0 ? scale_base[i,o] : scale_sp[i,o]*coef[i,o,t-1]
// ---------------------------------------------------------------------------
__global__ __launch_bounds__(256) void kan_prep_w(const float* __restrict__ sb,
                                                  const float* __restrict__ ssp,
                                                  const float* __restrict__ coef,
                                                  unsigned short* __restrict__ WT) {
  __shared__ unsigned short lds[9][32][33];
  int i0 = (blockIdx.x >> 5) * 32, o0 = (blockIdx.x & 31) * 32;
  int tid = threadIdx.x;
#pragma unroll
  for (int r = 0; r < 4; ++r) {
    int idx = r * 256 + tid;
    int ii = idx >> 5, oo = idx & 31;
    int io = (i0 + ii) * 1024 + (o0 + oo);
    float b = sb[io], s = ssp[io];
    const float4* cp = (const float4*)(coef + (size_t)io * 8);
    float4 c0 = cp[0], c1 = cp[1];
    lds[0][ii][oo] = f2bf(b);
    lds[1][ii][oo] = f2bf(s * c0.x);
    lds[2][ii][oo] = f2bf(s * c0.y);
    lds[3][ii][oo] = f2bf(s * c0.z);
    lds[4][ii][oo] = f2bf(s * c0.w);
    lds[5][ii][oo] = f2bf(s * c1.x);
    lds[6][ii][oo] = f2bf(s * c1.y);
    lds[7][ii][oo] = f2bf(s * c1.z);
    lds[8][ii][oo] = f2bf(s * c1.w);
  }
  __syncthreads();
#pragma unroll
  for (int r = 0; r < 4; ++r) {
    int idx = r * 256 + tid;
    int oo = idx >> 5, ii = idx & 31;
    size_t rowbase = (size_t)(o0 + oo) * KDIM + i0 + ii;
#pragma unroll
    for (int tp = 0; tp < 9; ++tp) WT[rowbase + tp * 1024] = lds[tp][ii][oo];
  }
}

// ---------------------------------------------------------------------------
// GEMM: C[4096][1024] = Ã[4096][9216] * W_T^T
// 128x64 tile, BK=64, 256 thr / 4 waves (2x2, 64x32 each), double-buffered LDS
// (48 KB -> 2+ blocks/CU), XOR-swizzled LDS (linear dest + pre-swizzled global
// source + swizzled ds_read), XCD-aware block swizzle.
// ---------------------------------------------------------------------------
#define BM 128
#define BN 64
#define BK 64
#define NT (KDIM / BK)   // 144

__global__ __launch_bounds__(256) void kan_gemm(const unsigned short* __restrict__ A,
                                                const unsigned short* __restrict__ BT,
                                                float* __restrict__ C) {
  __shared__ unsigned short As[2][BM * BK];   // 16 KB per buf
  __shared__ unsigned short Bs[2][BN * BK];   // 8 KB per buf
  const int tid = threadIdx.x;
  const int wid = tid >> 6, lane = tid & 63;
  const int wrM = wid >> 1, wcN = wid & 1;    // 2x2 wave grid -> 64x32 per wave
  const int row16 = lane & 15, kgrp = lane >> 4;
  const int rsw = (row16 & 7) << 3;           // elem-space read swizzle

  // XCD swizzle: 512 blocks, XCD x owns m in [4x,4x+4), all 16 n
  int wg = ((blockIdx.x & 7) << 6) | (blockIdx.x >> 3);
  const int m0 = (wg >> 4) * BM, n0 = (wg & 15) * BN;
  const size_t ldb = (size_t)KDIM * 2;
  const char* Ab = (const char*)A;
  const char* Bb = (const char*)BT;

  f32x4 acc[4][2] = {};

  auto stage = [&](int buf, int kt) {
    size_t kbyte = (size_t)kt * (BK * 2);
#pragma unroll
    for (int q = 0; q < 4; ++q) {             // A tile: 16 KB
      int d = q * 4096 + tid * 16;
      int row = d >> 7;
      int csw = (d & 127) ^ ((row & 7) << 4); // inverse-swizzled source col
      async_load16(Ab + (size_t)(m0 + row) * ldb + kbyte + csw,
                   (char*)(&As[buf][0]) + (q * 4096 + wid * 1024));
    }
#pragma unroll
    for (int q = 0; q < 2; ++q) {             // B tile: 8 KB
      int d = q * 4096 + tid * 16;
      int row = d >> 7;
      int csw = (d & 127) ^ ((row & 7) << 4);
      async_load16(Bb + (size_t)(n0 + row) * ldb + kbyte + csw,
                   (char*)(&Bs[buf][0]) + (q * 4096 + wid * 1024));
    }
  };

  stage(0, 0);
  __syncthreads();

  for (int kt = 0; kt < NT; ++kt) {
    int cur = kt & 1;
    if (kt + 1 < NT) stage(cur ^ 1, kt + 1);  // async prefetch next tile
    const unsigned short* as = &As[cur][0];
    const unsigned short* bs = &Bs[cur][0];
#pragma unroll
    for (int ks = 0; ks < 2; ++ks) {
      const int cbase = (ks * 32 + kgrp * 8) ^ rsw;
      bf16x8 af[4], bfr[2];
#pragma unroll
      for (int m = 0; m < 4; ++m)
        af[m] = *(const bf16x8*)(as + (wrM * 64 + m * 16 + row16) * BK + cbase);
#pragma unroll
      for (int n = 0; n < 2; ++n)
        bfr[n] = *(const bf16x8*)(bs + (wcN * 32 + n * 16 + row16) * BK + cbase);
#pragma unroll
      for (int m = 0; m < 4; ++m)
#pragma unroll
        for (int n = 0; n < 2; ++n)
          acc[m][n] = __builtin_amdgcn_mfma_f32_16x16x32_bf16(af[m], bfr[n], acc[m][n], 0, 0, 0);
    }
    __syncthreads();                          // drains prefetch + gates buf reuse
  }

  float* Cb = C + (size_t)(m0 + wrM * 64) * OUT_F + n0 + wcN * 32;
#pragma unroll
  for (int m = 0; m < 4; ++m)
#pragma unroll
    for (int n = 0; n < 2; ++n)
#pragma unroll
      for (int r = 0; r < 4; ++r) {
        int row = m * 16 + kgrp * 4 + r;      // C/D: row=(lane>>4)*4+reg
        int col = n * 16 + row16;             //      col=lane&15
        Cb[(size_t)row * OUT_F + col] = acc[m][n][r];
      }
}

// ---------------------------------------------------------------------------
// In-place LayerNorm over last dim (1024), one block per row.
// ---------------------------------------------------------------------------
__global__ __launch_bounds__(256) void kan_ln(float* __restrict__ y,
                                              const float* __restrict__ gamma,
                                              const float* __restrict__ beta) {
  __shared__ float ss[4], ssq[4];
  int tid = threadIdx.x;
  float4* p = (float4*)(y + (size_t)blockIdx.x * OUT_F);
  float4 v = p[tid];
  float s = v.x + v.y + v.z + v.w;
  float q = v.x * v.x + v.y * v.y + v.z * v.z + v.w * v.w;
#pragma unroll
  for (int off = 1; off < 64; off <<= 1) {
    s += __shfl_xor(s, off);
    q += __shfl_xor(q, off);
  }
  if ((tid & 63) == 0) { ss[tid >> 6] = s; ssq[tid >> 6] = q; }
  __syncthreads();
  float S = ss[0] + ss[1] + ss[2] + ss[3];
  float Q = ssq[0] + ssq[1] + ssq[2] + ssq[3];
  float mu  = S * (1.0f / OUT_F);
  float var = Q * (1.0f / OUT_F) - mu * mu;
  float inv = rsqrtf(var + 1e-5f);
  const float4 g  = ((const float4*)gamma)[tid];
  const float4 bt = ((const float4*)beta)[tid];
  float4 o;
  o.x = (v.x - mu) * inv * g.x + bt.x;
  o.y = (v.y - mu) * inv * g.y + bt.y;
  o.z = (v.z - mu) * inv * g.z + bt.z;
  o.w = (v.w - mu) * inv * g.w + bt.w;
  p[tid] = o;
}

extern "C" void kernel_launch(void* const* d_in, const int* in_sizes, int n_in,
                              void* d_out, int out_size, void* d_ws, size_t ws_size,
                              hipStream_t stream) {
  const float* x     = (const float*)d_in[0];
  const float* coef  = (const float*)d_in[1];
  const float* sb    = (const float*)d_in[2];
  const float* ssp   = (const float*)d_in[3];
  const float* gamma = (const float*)d_in[4];
  const float* beta  = (const float*)d_in[5];
  const float* grid  = (const float*)d_in[6];

  const size_t a_elems  = (size_t)BATCHN * KDIM;   // 75.5 MB bf16
  const size_t wt_elems = (size_t)OUT_F * KDIM;    // 18.9 MB bf16
  if (ws_size < (a_elems + wt_elems) * sizeof(unsigned short)) return;

  unsigned short* A  = (unsigned short*)d_ws;
  unsigned short* WT = A + a_elems;
  float* y = (float*)d_out;

  kan_prep_a<<<dim3((BATCHN * IN_F) / 256), dim3(256), 0, stream>>>(x, grid, A);
  kan_prep_w<<<dim3((IN_F / 32) * (OUT_F / 32)), dim3(256), 0, stream>>>(sb, ssp, coef, WT);
  kan_gemm<<<dim3((BATCHN / BM) * (OUT_F / BN)), dim3(256), 0, stream>>>(A, WT, y);
  kan_ln<<<dim3(BATCHN), dim3(256), 0, stream>>>(y, gamma, beta);
}

// Round 3
// 131.552 us; speedup vs baseline: 2.5685x; 1.3096x over previous
//
#include <hip/hip_runtime.h>

#define IN_F   1024
#define OUT_F  1024
#define BATCHN 4096
#define KDIM   9216   // 9 * 1024 (t-plane layout: k = t*1024 + i)

using bf16x8 = __attribute__((ext_vector_type(8))) __bf16;
using f32x4  = __attribute__((ext_vector_type(4))) float;

__device__ __forceinline__ unsigned short f2bf(float f) {
  union { float f; unsigned int u; } v; v.f = f;
  unsigned int u = v.u;
  unsigned int r = (u + 0x7FFFu + ((u >> 16) & 1u)) >> 16;  // RNE
  return (unsigned short)r;
}

__device__ __forceinline__ float bf2f(unsigned short h) {
  union { unsigned int u; float f; } v; v.u = ((unsigned int)h) << 16;
  return v.f;
}

__device__ __forceinline__ void async_load16(const void* g, void* l) {
  __builtin_amdgcn_global_load_lds(
      (__attribute__((address_space(1))) void*)(g),
      (__attribute__((address_space(3))) void*)(l),
      16, 0, 0);
}

// ---------------------------------------------------------------------------
// Ã[b][t*1024+i] : t=0 -> silu(x[b,i]); t=1..8 -> cubic B-spline basis values
// Uniform knots -> denominators are p*h: one rcp + multiplies (no v_div chains)
// ---------------------------------------------------------------------------
__global__ __launch_bounds__(256) void kan_prep_a(const float* __restrict__ x,
                                                  const float* __restrict__ grid,
                                                  unsigned short* __restrict__ A) {
  int idx = blockIdx.x * 256 + threadIdx.x;      // b*1024 + i, i fastest
  int i = idx & 1023;
  float xv = x[idx];
  float sil = xv / (1.0f + __expf(-xv));

  const float* g = grid + i * 12;
  float t[12];
#pragma unroll
  for (int j = 0; j < 12; ++j) t[j] = g[j];

  float B[11];
#pragma unroll
  for (int j = 0; j < 11; ++j) B[j] = (xv >= t[j] && xv < t[j + 1]) ? 1.0f : 0.0f;

  float inv_h = 1.0f / (t[4] - t[3]);            // uniform spacing
  const float invp[3] = {inv_h, inv_h * 0.5f, inv_h * (1.0f / 3.0f)};
#pragma unroll
  for (int p = 1; p <= 3; ++p) {
    float ip = invp[p - 1];
#pragma unroll
    for (int j = 0; j + p < 11; ++j)
      B[j] = (xv - t[j]) * ip * B[j] + (t[j + p + 1] - xv) * ip * B[j + 1];
  }

  size_t base = (size_t)(idx >> 10) * KDIM + i;
  A[base] = f2bf(sil);                            // t = 0 plane
#pragma unroll
  for (int k = 0; k < 8; ++k) A[base + (size_t)(k + 1) * 1024] = f2bf(B[k]);
}

// ---------------------------------------------------------------------------
// W_T[o][t*1024+i] = t==0 ? scale_base[i,o] : scale_sp[i,o]*coef[i,o,t-1]
// ---------------------------------------------------------------------------
__global__ __launch_bounds__(256) void kan_prep_w(const float* __restrict__ sb,
                                                  const float* __restrict__ ssp,
                                                  const float* __restrict__ coef,
                                                  unsigned short* __restrict__ WT) {
  __shared__ unsigned short lds[9][32][33];
  int i0 = (blockIdx.x >> 5) * 32, o0 = (blockIdx.x & 31) * 32;
  int tid = threadIdx.x;
#pragma unroll
  for (int r = 0; r < 4; ++r) {
    int idx = r * 256 + tid;
    int ii = idx >> 5, oo = idx & 31;
    int io = (i0 + ii) * 1024 + (o0 + oo);
    float b = sb[io], s = ssp[io];
    const float4* cp = (const float4*)(coef + (size_t)io * 8);
    float4 c0 = cp[0], c1 = cp[1];
    lds[0][ii][oo] = f2bf(b);
    lds[1][ii][oo] = f2bf(s * c0.x);
    lds[2][ii][oo] = f2bf(s * c0.y);
    lds[3][ii][oo] = f2bf(s * c0.z);
    lds[4][ii][oo] = f2bf(s * c0.w);
    lds[5][ii][oo] = f2bf(s * c1.x);
    lds[6][ii][oo] = f2bf(s * c1.y);
    lds[7][ii][oo] = f2bf(s * c1.z);
    lds[8][ii][oo] = f2bf(s * c1.w);
  }
  __syncthreads();
#pragma unroll
  for (int r = 0; r < 4; ++r) {
    int idx = r * 256 + tid;
    int oo = idx >> 5, ii = idx & 31;
    size_t rowbase = (size_t)(o0 + oo) * KDIM + i0 + ii;
#pragma unroll
    for (int tp = 0; tp < 9; ++tp) WT[rowbase + tp * 1024] = lds[tp][ii][oo];
  }
}

// ---------------------------------------------------------------------------
// GEMM with split-K=2: C_s[4096][1024] = Ã[:, sK/2:(s+1)K/2] * W_half
// 128x128 tile, BK=64, 256 thr / 4 waves (2x2, 64x64 each), dbuf LDS 64 KB
// (2 blocks/CU), XOR-swizzled LDS, XCD-aware block swizzle.
// s==1 -> fp32 to C (d_out); s==0 -> bf16 partial P0 (merged in kan_ln).
// ---------------------------------------------------------------------------
#define BM 128
#define BN 128
#define BK 64
#define KHALF (KDIM / 2)     // 4608
#define NTH (KHALF / BK)     // 72

__global__ __launch_bounds__(256) void kan_gemm(const unsigned short* __restrict__ A,
                                                const unsigned short* __restrict__ BT,
                                                float* __restrict__ C,
                                                unsigned short* __restrict__ P0) {
  __shared__ unsigned short As[2][BM * BK];   // 16 KB per buf
  __shared__ unsigned short Bs[2][BN * BK];   // 16 KB per buf
  const int tid = threadIdx.x;
  const int wid = tid >> 6, lane = tid & 63;
  const int wrM = wid >> 1, wcN = wid & 1;    // 2x2 wave grid -> 64x64 per wave
  const int row16 = lane & 15, kgrp = lane >> 4;
  const int rsw = (row16 & 7) << 3;           // elem-space read swizzle

  // XCD swizzle: 512 blocks; XCD x owns wg in [64x, 64x+64) = one contiguous
  // (s, m-panel) chunk (8 m-tiles x 8 n-tiles).
  int wg = ((blockIdx.x & 7) << 6) | (blockIdx.x >> 3);
  const int s = wg >> 8;                      // K-half
  const int m0 = ((wg >> 3) & 31) * BM, n0 = (wg & 7) * BN;
  const size_t ldb = (size_t)KDIM * 2;        // row stride bytes (A and BT)
  const size_t kbase = (size_t)s * (KHALF * 2);
  const char* Ab = (const char*)A;
  const char* Bb = (const char*)BT;

  f32x4 acc[4][4] = {};

  auto stage = [&](int buf, int kt) {
    size_t kbyte = kbase + (size_t)kt * (BK * 2);
#pragma unroll
    for (int q = 0; q < 4; ++q) {             // A tile: 16 KB
      int d = q * 4096 + tid * 16;
      int row = d >> 7;
      int csw = (d & 127) ^ ((row & 7) << 4); // inverse-swizzled source col
      async_load16(Ab + (size_t)(m0 + row) * ldb + kbyte + csw,
                   (char*)(&As[buf][0]) + (q * 4096 + wid * 1024));
    }
#pragma unroll
    for (int q = 0; q < 4; ++q) {             // B tile: 16 KB
      int d = q * 4096 + tid * 16;
      int row = d >> 7;
      int csw = (d & 127) ^ ((row & 7) << 4);
      async_load16(Bb + (size_t)(n0 + row) * ldb + kbyte + csw,
                   (char*)(&Bs[buf][0]) + (q * 4096 + wid * 1024));
    }
  };

  stage(0, 0);
  __syncthreads();

  for (int kt = 0; kt < NTH; ++kt) {
    int cur = kt & 1;
    if (kt + 1 < NTH) stage(cur ^ 1, kt + 1); // async prefetch next tile
    const unsigned short* as = &As[cur][0];
    const unsigned short* bs = &Bs[cur][0];
#pragma unroll
    for (int ks = 0; ks < 2; ++ks) {
      const int cbase = (ks * 32 + kgrp * 8) ^ rsw;
      bf16x8 af[4], bfr[4];
#pragma unroll
      for (int m = 0; m < 4; ++m)
        af[m] = *(const bf16x8*)(as + (wrM * 64 + m * 16 + row16) * BK + cbase);
#pragma unroll
      for (int n = 0; n < 4; ++n)
        bfr[n] = *(const bf16x8*)(bs + (wcN * 64 + n * 16 + row16) * BK + cbase);
#pragma unroll
      for (int m = 0; m < 4; ++m)
#pragma unroll
        for (int n = 0; n < 4; ++n)
          acc[m][n] = __builtin_amdgcn_mfma_f32_16x16x32_bf16(af[m], bfr[n], acc[m][n], 0, 0, 0);
    }
    __syncthreads();                          // drains prefetch + gates buf reuse
  }

  if (s == 1) {
    float* Cb = C + (size_t)(m0 + wrM * 64) * OUT_F + n0 + wcN * 64;
#pragma unroll
    for (int m = 0; m < 4; ++m)
#pragma unroll
      for (int n = 0; n < 4; ++n)
#pragma unroll
        for (int r = 0; r < 4; ++r)
          Cb[(size_t)(m * 16 + kgrp * 4 + r) * OUT_F + n * 16 + row16] = acc[m][n][r];
  } else {
    unsigned short* Pb = P0 + (size_t)(m0 + wrM * 64) * OUT_F + n0 + wcN * 64;
#pragma unroll
    for (int m = 0; m < 4; ++m)
#pragma unroll
      for (int n = 0; n < 4; ++n)
#pragma unroll
        for (int r = 0; r < 4; ++r)
          Pb[(size_t)(m * 16 + kgrp * 4 + r) * OUT_F + n * 16 + row16] = f2bf(acc[m][n][r]);
  }
}

// ---------------------------------------------------------------------------
// Merge split-K partial (bf16) + LayerNorm over last dim (1024), in-place.
// ---------------------------------------------------------------------------
__global__ __launch_bounds__(256) void kan_ln(float* __restrict__ y,
                                              const unsigned short* __restrict__ P0,
                                              const float* __restrict__ gamma,
                                              const float* __restrict__ beta) {
  __shared__ float ss[4], ssq[4];
  int tid = threadIdx.x;
  float4* p = (float4*)(y + (size_t)blockIdx.x * OUT_F);
  const ushort4 pv = ((const ushort4*)(P0 + (size_t)blockIdx.x * OUT_F))[tid];
  float4 v = p[tid];
  v.x += bf2f(pv.x);
  v.y += bf2f(pv.y);
  v.z += bf2f(pv.z);
  v.w += bf2f(pv.w);
  float s = v.x + v.y + v.z + v.w;
  float q = v.x * v.x + v.y * v.y + v.z * v.z + v.w * v.w;
#pragma unroll
  for (int off = 1; off < 64; off <<= 1) {
    s += __shfl_xor(s, off);
    q += __shfl_xor(q, off);
  }
  if ((tid & 63) == 0) { ss[tid >> 6] = s; ssq[tid >> 6] = q; }
  __syncthreads();
  float S = ss[0] + ss[1] + ss[2] + ss[3];
  float Q = ssq[0] + ssq[1] + ssq[2] + ssq[3];
  float mu  = S * (1.0f / OUT_F);
  float var = Q * (1.0f / OUT_F) - mu * mu;
  float inv = rsqrtf(var + 1e-5f);
  const float4 g  = ((const float4*)gamma)[tid];
  const float4 bt = ((const float4*)beta)[tid];
  float4 o;
  o.x = (v.x - mu) * inv * g.x + bt.x;
  o.y = (v.y - mu) * inv * g.y + bt.y;
  o.z = (v.z - mu) * inv * g.z + bt.z;
  o.w = (v.w - mu) * inv * g.w + bt.w;
  p[tid] = o;
}

extern "C" void kernel_launch(void* const* d_in, const int* in_sizes, int n_in,
                              void* d_out, int out_size, void* d_ws, size_t ws_size,
                              hipStream_t stream) {
  const float* x     = (const float*)d_in[0];
  const float* coef  = (const float*)d_in[1];
  const float* sb    = (const float*)d_in[2];
  const float* ssp   = (const float*)d_in[3];
  const float* gamma = (const float*)d_in[4];
  const float* beta  = (const float*)d_in[5];
  const float* grid  = (const float*)d_in[6];

  const size_t a_elems  = (size_t)BATCHN * KDIM;   // 75.5 MB bf16
  const size_t wt_elems = (size_t)OUT_F * KDIM;    // 18.9 MB bf16
  const size_t p0_elems = (size_t)BATCHN * OUT_F;  //  8.4 MB bf16
  if (ws_size < (a_elems + wt_elems + p0_elems) * sizeof(unsigned short)) return;

  unsigned short* A  = (unsigned short*)d_ws;
  unsigned short* WT = A + a_elems;
  unsigned short* P0 = WT + wt_elems;
  float* y = (float*)d_out;

  kan_prep_a<<<dim3((BATCHN * IN_F) / 256), dim3(256), 0, stream>>>(x, grid, A);
  kan_prep_w<<<dim3((IN_F / 32) * (OUT_F / 32)), dim3(256), 0, stream>>>(sb, ssp, coef, WT);
  kan_gemm<<<dim3(2 * (BATCHN / BM) * (OUT_F / BN)), dim3(256), 0, stream>>>(A, WT, y, P0);
  kan_ln<<<dim3(BATCHN), dim3(256), 0, stream>>>(y, P0, gamma, beta);
}

// Round 4
// 117.047 us; speedup vs baseline: 2.8868x; 1.1239x over previous
//
#include <hip/hip_runtime.h>

#define IN_F   1024
#define OUT_F  1024
#define BATCHN 4096
#define KDIM   9216   // 9 * 1024 (t-plane layout: k = t*1024 + i)

using bf16x8 = __attribute__((ext_vector_type(8))) __bf16;
using f32x4  = __attribute__((ext_vector_type(4))) float;

__device__ __forceinline__ unsigned short f2bf(float f) {
  union { float f; unsigned int u; } v; v.f = f;
  unsigned int u = v.u;
  unsigned int r = (u + 0x7FFFu + ((u >> 16) & 1u)) >> 16;  // RNE
  return (unsigned short)r;
}

__device__ __forceinline__ float bf2f(unsigned short h) {
  union { unsigned int u; float f; } v; v.u = ((unsigned int)h) << 16;
  return v.f;
}

__device__ __forceinline__ void async_load16(const void* g, void* l) {
  __builtin_amdgcn_global_load_lds(
      (__attribute__((address_space(1))) void*)(g),
      (__attribute__((address_space(3))) void*)(l),
      16, 0, 0);
}

// ---------------------------------------------------------------------------
// Ã[b][t*1024+i] : t=0 -> silu(x[b,i]); t=1..8 -> cubic B-spline basis values
// ---------------------------------------------------------------------------
__global__ __launch_bounds__(256) void kan_prep_a(const float* __restrict__ x,
                                                  const float* __restrict__ grid,
                                                  unsigned short* __restrict__ A) {
  int idx = blockIdx.x * 256 + threadIdx.x;      // b*1024 + i, i fastest
  int i = idx & 1023;
  float xv = x[idx];
  float sil = xv / (1.0f + __expf(-xv));

  const float* g = grid + i * 12;
  float t[12];
#pragma unroll
  for (int j = 0; j < 12; ++j) t[j] = g[j];

  float B[11];
#pragma unroll
  for (int j = 0; j < 11; ++j) B[j] = (xv >= t[j] && xv < t[j + 1]) ? 1.0f : 0.0f;

  float inv_h = 1.0f / (t[4] - t[3]);            // uniform spacing
  const float invp[3] = {inv_h, inv_h * 0.5f, inv_h * (1.0f / 3.0f)};
#pragma unroll
  for (int p = 1; p <= 3; ++p) {
    float ip = invp[p - 1];
#pragma unroll
    for (int j = 0; j + p < 11; ++j)
      B[j] = (xv - t[j]) * ip * B[j] + (t[j + p + 1] - xv) * ip * B[j + 1];
  }

  size_t base = (size_t)(idx >> 10) * KDIM + i;
  A[base] = f2bf(sil);                            // t = 0 plane
#pragma unroll
  for (int k = 0; k < 8; ++k) A[base + (size_t)(k + 1) * 1024] = f2bf(B[k]);
}

// ---------------------------------------------------------------------------
// W_T[o][t*1024+i] = t==0 ? scale_base[i,o] : scale_sp[i,o]*coef[i,o,t-1]
// ---------------------------------------------------------------------------
__global__ __launch_bounds__(256) void kan_prep_w(const float* __restrict__ sb,
                                                  const float* __restrict__ ssp,
                                                  const float* __restrict__ coef,
                                                  unsigned short* __restrict__ WT) {
  __shared__ unsigned short lds[9][32][33];
  int i0 = (blockIdx.x >> 5) * 32, o0 = (blockIdx.x & 31) * 32;
  int tid = threadIdx.x;
#pragma unroll
  for (int r = 0; r < 4; ++r) {
    int idx = r * 256 + tid;
    int ii = idx >> 5, oo = idx & 31;
    int io = (i0 + ii) * 1024 + (o0 + oo);
    float b = sb[io], s = ssp[io];
    const float4* cp = (const float4*)(coef + (size_t)io * 8);
    float4 c0 = cp[0], c1 = cp[1];
    lds[0][ii][oo] = f2bf(b);
    lds[1][ii][oo] = f2bf(s * c0.x);
    lds[2][ii][oo] = f2bf(s * c0.y);
    lds[3][ii][oo] = f2bf(s * c0.z);
    lds[4][ii][oo] = f2bf(s * c0.w);
    lds[5][ii][oo] = f2bf(s * c1.x);
    lds[6][ii][oo] = f2bf(s * c1.y);
    lds[7][ii][oo] = f2bf(s * c1.z);
    lds[8][ii][oo] = f2bf(s * c1.w);
  }
  __syncthreads();
#pragma unroll
  for (int r = 0; r < 4; ++r) {
    int idx = r * 256 + tid;
    int oo = idx >> 5, ii = idx & 31;
    size_t rowbase = (size_t)(o0 + oo) * KDIM + i0 + ii;
#pragma unroll
    for (int tp = 0; tp < 9; ++tp) WT[rowbase + tp * 1024] = lds[tp][ii][oo];
  }
}

// ---------------------------------------------------------------------------
// GEMM split-K=2, counted-vmcnt ring pipeline.
// BM=256 BN=128 BK=64, 512 thr / 8 waves (4Mx2N, 64x64 out per wave).
// LDS 128 KB: A ring-3 (3x32 KB, staged 2 slices ahead), B ring-2 (2x16 KB,
// staged 1 ahead). Per iter: vmcnt(4) [never 0] -> raw s_barrier ->
// sched_barrier -> stage B(sl+1), A(sl+2) -> ds_read -> setprio(1) 32 MFMA.
// Race-free: staged slots' readers completed before the barrier (each ds_read
// has an MFMA consumer behind a compiler lgkm wait preceding the barrier).
// ---------------------------------------------------------------------------
#define BM 256
#define BN 128
#define BK 64
#define KHALF  (KDIM / 2)    // 4608
#define NSL    (KHALF / BK)  // 72
#define A_SLOT (BM * BK)     // 16384 elems = 32 KB
#define B_SLOT (BN * BK)     // 8192 elems  = 16 KB

__global__ __launch_bounds__(512, 2) void kan_gemm(const unsigned short* __restrict__ A,
                                                   const unsigned short* __restrict__ BT,
                                                   float* __restrict__ C,
                                                   unsigned short* __restrict__ P0) {
  extern __shared__ unsigned short lds[];
  unsigned short* As = lds;                 // 3 * A_SLOT
  unsigned short* Bs = lds + 3 * A_SLOT;    // 2 * B_SLOT
  const int tid = threadIdx.x;
  const int wid = tid >> 6, lane = tid & 63;
  const int wr = wid >> 1, wc = wid & 1;    // 4x2 wave grid -> 64x64 per wave
  const int row16 = lane & 15, kgrp = lane >> 4;
  const int rsw = (row16 & 7) << 3;         // elem-space read swizzle

  // XCD swizzle: 256 blocks; XCD x owns wg in [32x,32x+32): fixed s, 4 m, all n
  int wg = ((blockIdx.x & 7) << 5) | (blockIdx.x >> 3);
  const int s = wg >> 7;
  const int m0 = ((wg >> 3) & 15) * BM, n0 = (wg & 7) * BN;
  const size_t ldb = (size_t)KDIM * 2;
  const size_t kbase = (size_t)s * (KHALF * 2);
  const char* Ab = (const char*)A;
  const char* Bb = (const char*)BT;

  f32x4 acc[4][4] = {};

  auto stageA = [&](int slot, int sl) {
    size_t kbyte = kbase + (size_t)sl * (BK * 2);
#pragma unroll
    for (int q = 0; q < 4; ++q) {           // 32 KB: 512 thr x 16B x 4
      int d = q * 8192 + tid * 16;
      int row = d >> 7;
      int csw = (d & 127) ^ ((row & 7) << 4);
      async_load16(Ab + (size_t)(m0 + row) * ldb + kbyte + csw,
                   (char*)(As + slot * A_SLOT) + (q * 8192 + wid * 1024));
    }
  };
  auto stageB = [&](int slot, int sl) {
    size_t kbyte = kbase + (size_t)sl * (BK * 2);
#pragma unroll
    for (int q = 0; q < 2; ++q) {           // 16 KB: 512 thr x 16B x 2
      int d = q * 8192 + tid * 16;
      int row = d >> 7;
      int csw = (d & 127) ^ ((row & 7) << 4);
      async_load16(Bb + (size_t)(n0 + row) * ldb + kbyte + csw,
                   (char*)(Bs + slot * B_SLOT) + (q * 8192 + wid * 1024));
    }
  };

  // Prologue queue: A(0)[4] B(0)[2] A(1)[4] -> iter0 vmcnt(4) clears A(0),B(0)
  stageA(0, 0);
  stageB(0, 0);
  stageA(1, 1);

  int consA = 0;                            // sl % 3
  for (int sl = 0; sl < NSL; ++sl) {
    if (sl < NSL - 1) asm volatile("s_waitcnt vmcnt(4)" ::: "memory");
    else              asm volatile("s_waitcnt vmcnt(0)" ::: "memory");
    __builtin_amdgcn_s_barrier();
    __builtin_amdgcn_sched_barrier(0);
    // stage order B-then-A keeps FIFO: queue = [A(sl+1), B(sl+1), A(sl+2)]
    if (sl + 1 < NSL) stageB((sl + 1) & 1, sl + 1);
    {
      int stgA = consA - 1; if (stgA < 0) stgA += 3;   // (sl+2) % 3
      if (sl + 2 < NSL) stageA(stgA, sl + 2);
    }
    const unsigned short* as = As + consA * A_SLOT;
    const unsigned short* bs = Bs + (sl & 1) * B_SLOT;
    bf16x8 af[2][4], bfr[2][4];
#pragma unroll
    for (int ks = 0; ks < 2; ++ks) {
      const int cb = (ks * 32 + kgrp * 8) ^ rsw;
#pragma unroll
      for (int m = 0; m < 4; ++m)
        af[ks][m] = *(const bf16x8*)(as + (wr * 64 + m * 16 + row16) * BK + cb);
#pragma unroll
      for (int n = 0; n < 4; ++n)
        bfr[ks][n] = *(const bf16x8*)(bs + (wc * 64 + n * 16 + row16) * BK + cb);
    }
    __builtin_amdgcn_s_setprio(1);
#pragma unroll
    for (int ks = 0; ks < 2; ++ks)
#pragma unroll
      for (int m = 0; m < 4; ++m)
#pragma unroll
        for (int n = 0; n < 4; ++n)
          acc[m][n] = __builtin_amdgcn_mfma_f32_16x16x32_bf16(af[ks][m], bfr[ks][n], acc[m][n], 0, 0, 0);
    __builtin_amdgcn_s_setprio(0);
    consA = (consA == 2) ? 0 : consA + 1;
  }

  if (s == 1) {
    float* Cb = C + (size_t)(m0 + wr * 64) * OUT_F + n0 + wc * 64;
#pragma unroll
    for (int m = 0; m < 4; ++m)
#pragma unroll
      for (int n = 0; n < 4; ++n)
#pragma unroll
        for (int r = 0; r < 4; ++r)
          Cb[(size_t)(m * 16 + kgrp * 4 + r) * OUT_F + n * 16 + row16] = acc[m][n][r];
  } else {
    unsigned short* Pb = P0 + (size_t)(m0 + wr * 64) * OUT_F + n0 + wc * 64;
#pragma unroll
    for (int m = 0; m < 4; ++m)
#pragma unroll
      for (int n = 0; n < 4; ++n)
#pragma unroll
        for (int r = 0; r < 4; ++r)
          Pb[(size_t)(m * 16 + kgrp * 4 + r) * OUT_F + n * 16 + row16] = f2bf(acc[m][n][r]);
  }
}

// ---------------------------------------------------------------------------
// Merge split-K partial (bf16) + LayerNorm over last dim (1024), in-place.
// ---------------------------------------------------------------------------
__global__ __launch_bounds__(256) void kan_ln(float* __restrict__ y,
                                              const unsigned short* __restrict__ P0,
                                              const float* __restrict__ gamma,
                                              const float* __restrict__ beta) {
  __shared__ float ss[4], ssq[4];
  int tid = threadIdx.x;
  float4* p = (float4*)(y + (size_t)blockIdx.x * OUT_F);
  const ushort4 pv = ((const ushort4*)(P0 + (size_t)blockIdx.x * OUT_F))[tid];
  float4 v = p[tid];
  v.x += bf2f(pv.x);
  v.y += bf2f(pv.y);
  v.z += bf2f(pv.z);
  v.w += bf2f(pv.w);
  float s = v.x + v.y + v.z + v.w;
  float q = v.x * v.x + v.y * v.y + v.z * v.z + v.w * v.w;
#pragma unroll
  for (int off = 1; off < 64; off <<= 1) {
    s += __shfl_xor(s, off);
    q += __shfl_xor(q, off);
  }
  if ((tid & 63) == 0) { ss[tid >> 6] = s; ssq[tid >> 6] = q; }
  __syncthreads();
  float S = ss[0] + ss[1] + ss[2] + ss[3];
  float Q = ssq[0] + ssq[1] + ssq[2] + ssq[3];
  float mu  = S * (1.0f / OUT_F);
  float var = Q * (1.0f / OUT_F) - mu * mu;
  float inv = rsqrtf(var + 1e-5f);
  const float4 g  = ((const float4*)gamma)[tid];
  const float4 bt = ((const float4*)beta)[tid];
  float4 o;
  o.x = (v.x - mu) * inv * g.x + bt.x;
  o.y = (v.y - mu) * inv * g.y + bt.y;
  o.z = (v.z - mu) * inv * g.z + bt.z;
  o.w = (v.w - mu) * inv * g.w + bt.w;
  p[tid] = o;
}

extern "C" void kernel_launch(void* const* d_in, const int* in_sizes, int n_in,
                              void* d_out, int out_size, void* d_ws, size_t ws_size,
                              hipStream_t stream) {
  const float* x     = (const float*)d_in[0];
  const float* coef  = (const float*)d_in[1];
  const float* sb    = (const float*)d_in[2];
  const float* ssp   = (const float*)d_in[3];
  const float* gamma = (const float*)d_in[4];
  const float* beta  = (const float*)d_in[5];
  const float* grid  = (const float*)d_in[6];

  const size_t a_elems  = (size_t)BATCHN * KDIM;   // 75.5 MB bf16
  const size_t wt_elems = (size_t)OUT_F * KDIM;    // 18.9 MB bf16
  const size_t p0_elems = (size_t)BATCHN * OUT_F;  //  8.4 MB bf16
  if (ws_size < (a_elems + wt_elems + p0_elems) * sizeof(unsigned short)) return;

  unsigned short* A  = (unsigned short*)d_ws;
  unsigned short* WT = A + a_elems;
  unsigned short* P0 = WT + wt_elems;
  float* y = (float*)d_out;

  const size_t lds_bytes = (3 * (size_t)A_SLOT + 2 * (size_t)B_SLOT) * sizeof(unsigned short); // 128 KB

  kan_prep_a<<<dim3((BATCHN * IN_F) / 256), dim3(256), 0, stream>>>(x, grid, A);
  kan_prep_w<<<dim3((IN_F / 32) * (OUT_F / 32)), dim3(256), 0, stream>>>(sb, ssp, coef, WT);
  kan_gemm<<<dim3(2 * (BATCHN / BM) * (OUT_F / BN)), dim3(512), lds_bytes, stream>>>(A, WT, y, P0);
  kan_ln<<<dim3(BATCHN), dim3(256), 0, stream>>>(y, P0, gamma, beta);
}

// Round 5
// 116.201 us; speedup vs baseline: 2.9078x; 1.0073x over previous
//
#include <hip/hip_runtime.h>

#define IN_F   1024
#define OUT_F  1024
#define BATCHN 4096
#define KDIM   9216   // 9 * 1024 (t-plane layout: k = t*1024 + i)

using bf16x8 = __attribute__((ext_vector_type(8))) __bf16;
using f32x4  = __attribute__((ext_vector_type(4))) float;

__device__ __forceinline__ unsigned short f2bf(float f) {
  union { float f; unsigned int u; } v; v.f = f;
  unsigned int u = v.u;
  unsigned int r = (u + 0x7FFFu + ((u >> 16) & 1u)) >> 16;  // RNE
  return (unsigned short)r;
}

__device__ __forceinline__ float bf2f(unsigned short h) {
  union { unsigned int u; float f; } v; v.u = ((unsigned int)h) << 16;
  return v.f;
}

__device__ __forceinline__ void async_load16(const void* g, void* l) {
  __builtin_amdgcn_global_load_lds(
      (__attribute__((address_space(1))) void*)(g),
      (__attribute__((address_space(3))) void*)(l),
      16, 0, 0);
}

// ---------------------------------------------------------------------------
// Ã[b][t*1024+i] : t=0 -> silu(x[b,i]); t=1..8 -> cubic B-spline basis values
// ---------------------------------------------------------------------------
__global__ __launch_bounds__(256) void kan_prep_a(const float* __restrict__ x,
                                                  const float* __restrict__ grid,
                                                  unsigned short* __restrict__ A) {
  int idx = blockIdx.x * 256 + threadIdx.x;      // b*1024 + i, i fastest
  int i = idx & 1023;
  float xv = x[idx];
  float sil = xv / (1.0f + __expf(-xv));

  const float* g = grid + i * 12;
  float t[12];
#pragma unroll
  for (int j = 0; j < 12; ++j) t[j] = g[j];

  float B[11];
#pragma unroll
  for (int j = 0; j < 11; ++j) B[j] = (xv >= t[j] && xv < t[j + 1]) ? 1.0f : 0.0f;

  float inv_h = 1.0f / (t[4] - t[3]);            // uniform spacing
  const float invp[3] = {inv_h, inv_h * 0.5f, inv_h * (1.0f / 3.0f)};
#pragma unroll
  for (int p = 1; p <= 3; ++p) {
    float ip = invp[p - 1];
#pragma unroll
    for (int j = 0; j + p < 11; ++j)
      B[j] = (xv - t[j]) * ip * B[j] + (t[j + p + 1] - xv) * ip * B[j + 1];
  }

  size_t base = (size_t)(idx >> 10) * KDIM + i;
  A[base] = f2bf(sil);                            // t = 0 plane
#pragma unroll
  for (int k = 0; k < 8; ++k) A[base + (size_t)(k + 1) * 1024] = f2bf(B[k]);
}

// ---------------------------------------------------------------------------
// W_T[o][t*1024+i] = t==0 ? scale_base[i,o] : scale_sp[i,o]*coef[i,o,t-1]
// ---------------------------------------------------------------------------
__global__ __launch_bounds__(256) void kan_prep_w(const float* __restrict__ sb,
                                                  const float* __restrict__ ssp,
                                                  const float* __restrict__ coef,
                                                  unsigned short* __restrict__ WT) {
  __shared__ unsigned short lds[9][32][33];
  int i0 = (blockIdx.x >> 5) * 32, o0 = (blockIdx.x & 31) * 32;
  int tid = threadIdx.x;
#pragma unroll
  for (int r = 0; r < 4; ++r) {
    int idx = r * 256 + tid;
    int ii = idx >> 5, oo = idx & 31;
    int io = (i0 + ii) * 1024 + (o0 + oo);
    float b = sb[io], s = ssp[io];
    const float4* cp = (const float4*)(coef + (size_t)io * 8);
    float4 c0 = cp[0], c1 = cp[1];
    lds[0][ii][oo] = f2bf(b);
    lds[1][ii][oo] = f2bf(s * c0.x);
    lds[2][ii][oo] = f2bf(s * c0.y);
    lds[3][ii][oo] = f2bf(s * c0.z);
    lds[4][ii][oo] = f2bf(s * c0.w);
    lds[5][ii][oo] = f2bf(s * c1.x);
    lds[6][ii][oo] = f2bf(s * c1.y);
    lds[7][ii][oo] = f2bf(s * c1.z);
    lds[8][ii][oo] = f2bf(s * c1.w);
  }
  __syncthreads();
#pragma unroll
  for (int r = 0; r < 4; ++r) {
    int idx = r * 256 + tid;
    int oo = idx >> 5, ii = idx & 31;
    size_t rowbase = (size_t)(o0 + oo) * KDIM + i0 + ii;
#pragma unroll
    for (int tp = 0; tp < 9; ++tp) WT[rowbase + tp * 1024] = lds[tp][ii][oo];
  }
}

// ---------------------------------------------------------------------------
// GEMM split-K=4, counted-vmcnt ring pipeline.
// BM=256 BN=256 BK=64, 512 thr / 8 waves (2Mx4N, 128x64 out per wave).
// LDS 160 KiB: A ring-3 (3x32 KiB, 2 ahead), B ring-2 (2x32 KiB, 1 ahead).
// Per iter: vmcnt(4) [A(sl+1) stays in flight] -> s_barrier -> sched_barrier
// -> stage B(sl+1), A(sl+2) -> per-ks {12 ds_read_b128 -> setprio 32 MFMA}.
// s==3 writes fp32 to C; s<3 write bf16 partials P[s] (merged in kan_ln).
// ---------------------------------------------------------------------------
#define BM 256
#define BN 256
#define BK 64
#define KQ     (KDIM / 4)    // 2304 per split-K group
#define NSL    (KQ / BK)     // 36
#define A_SLOT (BM * BK)     // 16384 elems = 32 KiB
#define B_SLOT (BN * BK)     // 16384 elems = 32 KiB

__global__ __launch_bounds__(512, 2) void kan_gemm(const unsigned short* __restrict__ A,
                                                   const unsigned short* __restrict__ BT,
                                                   float* __restrict__ C,
                                                   unsigned short* __restrict__ P) {
  extern __shared__ unsigned short lds[];
  unsigned short* As = lds;                 // 3 * A_SLOT
  unsigned short* Bs = lds + 3 * A_SLOT;    // 2 * B_SLOT
  const int tid = threadIdx.x;
  const int wid = tid >> 6, lane = tid & 63;
  const int wr = wid >> 2, wc = wid & 3;    // 2x4 wave grid -> 128x64 per wave
  const int row16 = lane & 15, kgrp = lane >> 4;
  const int rsw = (row16 & 7) << 3;         // elem-space read swizzle

  // XCD swizzle: 256 blocks; XCD x owns wg in [32x,32x+32): fixed s, 8 m, 4 n
  int wg = ((blockIdx.x & 7) << 5) | (blockIdx.x >> 3);
  const int s = wg >> 6;
  const int m0 = ((wg >> 2) & 15) * BM, n0 = (wg & 3) * BN;
  const size_t ldb = (size_t)KDIM * 2;
  const size_t kbase = (size_t)s * (KQ * 2);
  const char* Ab = (const char*)A;
  const char* Bb = (const char*)BT;

  f32x4 acc[8][4] = {};

  auto stage = [&](const char* Gb, int grow0, unsigned short* slotp, int sl) {
    size_t kbyte = kbase + (size_t)sl * (BK * 2);
#pragma unroll
    for (int q = 0; q < 4; ++q) {           // 32 KiB: 512 thr x 16B x 4
      int d = q * 8192 + tid * 16;
      int row = d >> 7;
      int csw = (d & 127) ^ ((row & 7) << 4);
      async_load16(Gb + (size_t)(grow0 + row) * ldb + kbyte + csw,
                   (char*)slotp + (q * 8192 + wid * 1024));
    }
  };

  // Prologue FIFO: A(0)[4] B(0)[4] A(1)[4] -> iter0 vmcnt(4) clears A(0),B(0)
  stage(Ab, m0, As, 0);
  stage(Bb, n0, Bs, 0);
  stage(Ab, m0, As + A_SLOT, 1);

  int consA = 0;                            // sl % 3
  for (int sl = 0; sl < NSL; ++sl) {
    if (sl < NSL - 1) asm volatile("s_waitcnt vmcnt(4)" ::: "memory");
    else              asm volatile("s_waitcnt vmcnt(0)" ::: "memory");
    __builtin_amdgcn_s_barrier();
    __builtin_amdgcn_sched_barrier(0);
    // FIFO order B-then-A: queue = [A(sl+1), B(sl+1), A(sl+2)]
    if (sl + 1 < NSL) stage(Bb, n0, Bs + ((sl + 1) & 1) * B_SLOT, sl + 1);
    {
      int stgA = consA - 1; if (stgA < 0) stgA += 3;   // (sl+2) % 3
      if (sl + 2 < NSL) stage(Ab, m0, As + stgA * A_SLOT, sl + 2);
    }
    const unsigned short* as = As + consA * A_SLOT;
    const unsigned short* bs = Bs + (sl & 1) * B_SLOT;
#pragma unroll
    for (int ks = 0; ks < 2; ++ks) {
      const int cb = (ks * 32 + kgrp * 8) ^ rsw;
      bf16x8 af[8], bfr[4];
#pragma unroll
      for (int m = 0; m < 8; ++m)
        af[m] = *(const bf16x8*)(as + (wr * 128 + m * 16 + row16) * BK + cb);
#pragma unroll
      for (int n = 0; n < 4; ++n)
        bfr[n] = *(const bf16x8*)(bs + (wc * 64 + n * 16 + row16) * BK + cb);
      __builtin_amdgcn_s_setprio(1);
#pragma unroll
      for (int m = 0; m < 8; ++m)
#pragma unroll
        for (int n = 0; n < 4; ++n)
          acc[m][n] = __builtin_amdgcn_mfma_f32_16x16x32_bf16(af[m], bfr[n], acc[m][n], 0, 0, 0);
      __builtin_amdgcn_s_setprio(0);
    }
    consA = (consA == 2) ? 0 : consA + 1;
  }

  if (s == 3) {
    float* Cb = C + (size_t)(m0 + wr * 128) * OUT_F + n0 + wc * 64;
#pragma unroll
    for (int m = 0; m < 8; ++m)
#pragma unroll
      for (int n = 0; n < 4; ++n)
#pragma unroll
        for (int r = 0; r < 4; ++r)
          Cb[(size_t)(m * 16 + kgrp * 4 + r) * OUT_F + n * 16 + row16] = acc[m][n][r];
  } else {
    unsigned short* Pb = P + (size_t)s * BATCHN * OUT_F
                       + (size_t)(m0 + wr * 128) * OUT_F + n0 + wc * 64;
#pragma unroll
    for (int m = 0; m < 8; ++m)
#pragma unroll
      for (int n = 0; n < 4; ++n)
#pragma unroll
        for (int r = 0; r < 4; ++r)
          Pb[(size_t)(m * 16 + kgrp * 4 + r) * OUT_F + n * 16 + row16] = f2bf(acc[m][n][r]);
  }
}

// ---------------------------------------------------------------------------
// Merge split-K partials (3x bf16) + LayerNorm over last dim (1024), in-place.
// ---------------------------------------------------------------------------
__global__ __launch_bounds__(256) void kan_ln(float* __restrict__ y,
                                              const unsigned short* __restrict__ P,
                                              const float* __restrict__ gamma,
                                              const float* __restrict__ beta) {
  __shared__ float ss[4], ssq[4];
  int tid = threadIdx.x;
  float4* p = (float4*)(y + (size_t)blockIdx.x * OUT_F);
  float4 v = p[tid];
#pragma unroll
  for (int pp = 0; pp < 3; ++pp) {
    const ushort4 pv = ((const ushort4*)(P + (size_t)pp * BATCHN * OUT_F
                                           + (size_t)blockIdx.x * OUT_F))[tid];
    v.x += bf2f(pv.x);
    v.y += bf2f(pv.y);
    v.z += bf2f(pv.z);
    v.w += bf2f(pv.w);
  }
  float s = v.x + v.y + v.z + v.w;
  float q = v.x * v.x + v.y * v.y + v.z * v.z + v.w * v.w;
#pragma unroll
  for (int off = 1; off < 64; off <<= 1) {
    s += __shfl_xor(s, off);
    q += __shfl_xor(q, off);
  }
  if ((tid & 63) == 0) { ss[tid >> 6] = s; ssq[tid >> 6] = q; }
  __syncthreads();
  float S = ss[0] + ss[1] + ss[2] + ss[3];
  float Q = ssq[0] + ssq[1] + ssq[2] + ssq[3];
  float mu  = S * (1.0f / OUT_F);
  float var = Q * (1.0f / OUT_F) - mu * mu;
  float inv = rsqrtf(var + 1e-5f);
  const float4 g  = ((const float4*)gamma)[tid];
  const float4 bt = ((const float4*)beta)[tid];
  float4 o;
  o.x = (v.x - mu) * inv * g.x + bt.x;
  o.y = (v.y - mu) * inv * g.y + bt.y;
  o.z = (v.z - mu) * inv * g.z + bt.z;
  o.w = (v.w - mu) * inv * g.w + bt.w;
  p[tid] = o;
}

extern "C" void kernel_launch(void* const* d_in, const int* in_sizes, int n_in,
                              void* d_out, int out_size, void* d_ws, size_t ws_size,
                              hipStream_t stream) {
  const float* x     = (const float*)d_in[0];
  const float* coef  = (const float*)d_in[1];
  const float* sb    = (const float*)d_in[2];
  const float* ssp   = (const float*)d_in[3];
  const float* gamma = (const float*)d_in[4];
  const float* beta  = (const float*)d_in[5];
  const float* grid  = (const float*)d_in[6];

  const size_t a_elems  = (size_t)BATCHN * KDIM;       // 75.5 MB bf16
  const size_t wt_elems = (size_t)OUT_F * KDIM;        // 18.9 MB bf16
  const size_t p_elems  = (size_t)3 * BATCHN * OUT_F;  // 25.2 MB bf16
  if (ws_size < (a_elems + wt_elems + p_elems) * sizeof(unsigned short)) return;

  unsigned short* A  = (unsigned short*)d_ws;
  unsigned short* WT = A + a_elems;
  unsigned short* P  = WT + wt_elems;
  float* y = (float*)d_out;

  const size_t lds_bytes = (3 * (size_t)A_SLOT + 2 * (size_t)B_SLOT) * sizeof(unsigned short); // 160 KiB
  static bool attr_set = false;
  if (!attr_set) {
    hipFuncSetAttribute((const void*)kan_gemm,
                        hipFuncAttributeMaxDynamicSharedMemorySize, (int)lds_bytes);
    attr_set = true;
  }

  kan_prep_a<<<dim3((BATCHN * IN_F) / 256), dim3(256), 0, stream>>>(x, grid, A);
  kan_prep_w<<<dim3((IN_F / 32) * (OUT_F / 32)), dim3(256), 0, stream>>>(sb, ssp, coef, WT);
  kan_gemm<<<dim3(4 * (BATCHN / BM) * (OUT_F / BN)), dim3(512), lds_bytes, stream>>>(A, WT, y, P);
  kan_ln<<<dim3(BATCHN), dim3(256), 0, stream>>>(y, P, gamma, beta);
}

// Round 6
// 115.383 us; speedup vs baseline: 2.9285x; 1.0071x over previous
//
#include <hip/hip_runtime.h>

#define IN_F   1024
#define OUT_F  1024
#define BATCHN 4096
#define KDIM   9216   // 9 * 1024 (t-plane layout: k = t*1024 + i)

using bf16x8 = __attribute__((ext_vector_type(8))) __bf16;
using f32x4  = __attribute__((ext_vector_type(4))) float;

__device__ __forceinline__ unsigned short f2bf(float f) {
  union { float f; unsigned int u; } v; v.f = f;
  unsigned int u = v.u;
  unsigned int r = (u + 0x7FFFu + ((u >> 16) & 1u)) >> 16;  // RNE
  return (unsigned short)r;
}

__device__ __forceinline__ float bf2f(unsigned short h) {
  union { unsigned int u; float f; } v; v.u = ((unsigned int)h) << 16;
  return v.f;
}

__device__ __forceinline__ void async_load16(const void* g, void* l) {
  __builtin_amdgcn_global_load_lds(
      (__attribute__((address_space(1))) void*)(g),
      (__attribute__((address_space(3))) void*)(l),
      16, 0, 0);
}

// ---------------------------------------------------------------------------
// Ã[b][t*1024+i] : t=0 -> silu(x[b,i]); t=1..8 -> cubic B-spline basis values
// ---------------------------------------------------------------------------
__global__ __launch_bounds__(256) void kan_prep_a(const float* __restrict__ x,
                                                  const float* __restrict__ grid,
                                                  unsigned short* __restrict__ A) {
  int idx = blockIdx.x * 256 + threadIdx.x;      // b*1024 + i, i fastest
  int i = idx & 1023;
  float xv = x[idx];
  float sil = xv / (1.0f + __expf(-xv));

  const float* g = grid + i * 12;
  float t[12];
#pragma unroll
  for (int j = 0; j < 12; ++j) t[j] = g[j];

  float B[11];
#pragma unroll
  for (int j = 0; j < 11; ++j) B[j] = (xv >= t[j] && xv < t[j + 1]) ? 1.0f : 0.0f;

  float inv_h = 1.0f / (t[4] - t[3]);            // uniform spacing
  const float invp[3] = {inv_h, inv_h * 0.5f, inv_h * (1.0f / 3.0f)};
#pragma unroll
  for (int p = 1; p <= 3; ++p) {
    float ip = invp[p - 1];
#pragma unroll
    for (int j = 0; j + p < 11; ++j)
      B[j] = (xv - t[j]) * ip * B[j] + (t[j + p + 1] - xv) * ip * B[j + 1];
  }

  size_t base = (size_t)(idx >> 10) * KDIM + i;
  A[base] = f2bf(sil);                            // t = 0 plane
#pragma unroll
  for (int k = 0; k < 8; ++k) A[base + (size_t)(k + 1) * 1024] = f2bf(B[k]);
}

// ---------------------------------------------------------------------------
// W_T[o][t*1024+i] = t==0 ? scale_base[i,o] : scale_sp[i,o]*coef[i,o,t-1]
// ---------------------------------------------------------------------------
__global__ __launch_bounds__(256) void kan_prep_w(const float* __restrict__ sb,
                                                  const float* __restrict__ ssp,
                                                  const float* __restrict__ coef,
                                                  unsigned short* __restrict__ WT) {
  __shared__ unsigned short lds[9][32][33];
  int i0 = (blockIdx.x >> 5) * 32, o0 = (blockIdx.x & 31) * 32;
  int tid = threadIdx.x;
#pragma unroll
  for (int r = 0; r < 4; ++r) {
    int idx = r * 256 + tid;
    int ii = idx >> 5, oo = idx & 31;
    int io = (i0 + ii) * 1024 + (o0 + oo);
    float b = sb[io], s = ssp[io];
    const float4* cp = (const float4*)(coef + (size_t)io * 8);
    float4 c0 = cp[0], c1 = cp[1];
    lds[0][ii][oo] = f2bf(b);
    lds[1][ii][oo] = f2bf(s * c0.x);
    lds[2][ii][oo] = f2bf(s * c0.y);
    lds[3][ii][oo] = f2bf(s * c0.z);
    lds[4][ii][oo] = f2bf(s * c0.w);
    lds[5][ii][oo] = f2bf(s * c1.x);
    lds[6][ii][oo] = f2bf(s * c1.y);
    lds[7][ii][oo] = f2bf(s * c1.z);
    lds[8][ii][oo] = f2bf(s * c1.w);
  }
  __syncthreads();
#pragma unroll
  for (int r = 0; r < 4; ++r) {
    int idx = r * 256 + tid;
    int oo = idx >> 5, ii = idx & 31;
    size_t rowbase = (size_t)(o0 + oo) * KDIM + i0 + ii;
#pragma unroll
    for (int tp = 0; tp < 9; ++tp) WT[rowbase + tp * 1024] = lds[tp][ii][oo];
  }
}

// ---------------------------------------------------------------------------
// GEMM split-K=4, counted-vmcnt ring + 4-phase fine interleave (m201-style).
// BM=256 BN=256 BK=64, 512 thr / 8 waves (2Mx4N, 128x64 out per wave).
// LDS 160 KiB: A ring-3 (2 ahead), B ring-2 (1 ahead).
// Per iter: vmcnt(4) -> barrier -> 4 phases of
//   {reads (4-8 ds_read_b128) ; [stage B / stage A] ; barrier ;
//    setprio(1) 16 MFMA setprio(0)}
// so each cluster's reads land during the preceding barrier wait.
// ---------------------------------------------------------------------------
#define BM 256
#define BN 256
#define BK 64
#define KQ     (KDIM / 4)    // 2304 per split-K group
#define NSL    (KQ / BK)     // 36
#define A_SLOT (BM * BK)     // 16384 elems = 32 KiB
#define B_SLOT (BN * BK)     // 16384 elems = 32 KiB

__global__ __launch_bounds__(512, 2) void kan_gemm(const unsigned short* __restrict__ A,
                                                   const unsigned short* __restrict__ BT,
                                                   float* __restrict__ C,
                                                   unsigned short* __restrict__ P) {
  extern __shared__ unsigned short lds[];
  unsigned short* As = lds;                 // 3 * A_SLOT
  unsigned short* Bs = lds + 3 * A_SLOT;    // 2 * B_SLOT
  const int tid = threadIdx.x;
  const int wid = tid >> 6, lane = tid & 63;
  const int wr = wid >> 2, wc = wid & 3;    // 2x4 wave grid -> 128x64 per wave
  const int row16 = lane & 15, kgrp = lane >> 4;
  const int rsw = (row16 & 7) << 3;         // elem-space read swizzle

  // XCD swizzle: 256 blocks; XCD x owns wg in [32x,32x+32): fixed s, 8 m, 4 n
  int wg = ((blockIdx.x & 7) << 5) | (blockIdx.x >> 3);
  const int s = wg >> 6;
  const int m0 = ((wg >> 2) & 15) * BM, n0 = (wg & 3) * BN;
  const size_t ldb = (size_t)KDIM * 2;
  const size_t kbase = (size_t)s * (KQ * 2);
  const char* Ab = (const char*)A;
  const char* Bb = (const char*)BT;

  f32x4 acc[8][4] = {};

  auto stage = [&](const char* Gb, int grow0, unsigned short* slotp, int sl) {
    size_t kbyte = kbase + (size_t)sl * (BK * 2);
#pragma unroll
    for (int q = 0; q < 4; ++q) {           // 32 KiB: 512 thr x 16B x 4
      int d = q * 8192 + tid * 16;
      int row = d >> 7;
      int csw = (d & 127) ^ ((row & 7) << 4);
      async_load16(Gb + (size_t)(grow0 + row) * ldb + kbyte + csw,
                   (char*)slotp + (q * 8192 + wid * 1024));
    }
  };

  // Prologue FIFO: A(0)[4] B(0)[4] A(1)[4] -> iter0 vmcnt(4) clears A(0),B(0)
  stage(Ab, m0, As, 0);
  stage(Bb, n0, Bs, 0);
  stage(Ab, m0, As + A_SLOT, 1);

  int consA = 0;                            // sl % 3
  for (int sl = 0; sl < NSL; ++sl) {
    if (sl < NSL - 1) asm volatile("s_waitcnt vmcnt(4)" ::: "memory");
    else              asm volatile("s_waitcnt vmcnt(0)" ::: "memory");
    __builtin_amdgcn_s_barrier();
    __builtin_amdgcn_sched_barrier(0);
    const unsigned short* as = As + consA * A_SLOT;
    const unsigned short* bs = Bs + (sl & 1) * B_SLOT;
    const int cb0 = (kgrp * 8) ^ rsw;       // ks=0
    const int cb1 = (32 + kgrp * 8) ^ rsw;  // ks=1

    // ---- phase 0: B(ks0) + A-low(ks0); stage B(sl+1) ----
    bf16x8 b0[4], a0[4];
#pragma unroll
    for (int n = 0; n < 4; ++n)
      b0[n] = *(const bf16x8*)(bs + (wc * 64 + n * 16 + row16) * BK + cb0);
#pragma unroll
    for (int m = 0; m < 4; ++m)
      a0[m] = *(const bf16x8*)(as + (wr * 128 + m * 16 + row16) * BK + cb0);
    if (sl + 1 < NSL) stage(Bb, n0, Bs + ((sl + 1) & 1) * B_SLOT, sl + 1);
    __builtin_amdgcn_sched_barrier(0);
    __builtin_amdgcn_s_barrier();
    __builtin_amdgcn_s_setprio(1);
#pragma unroll
    for (int m = 0; m < 4; ++m)
#pragma unroll
      for (int n = 0; n < 4; ++n)
        acc[m][n] = __builtin_amdgcn_mfma_f32_16x16x32_bf16(a0[m], b0[n], acc[m][n], 0, 0, 0);
    __builtin_amdgcn_s_setprio(0);

    // ---- phase 1: A-high(ks0); stage A(sl+2) ----
    bf16x8 a1[4];
#pragma unroll
    for (int m = 0; m < 4; ++m)
      a1[m] = *(const bf16x8*)(as + (wr * 128 + (m + 4) * 16 + row16) * BK + cb0);
    {
      int stgA = consA - 1; if (stgA < 0) stgA += 3;   // (sl+2) % 3
      if (sl + 2 < NSL) stage(Ab, m0, As + stgA * A_SLOT, sl + 2);
    }
    __builtin_amdgcn_sched_barrier(0);
    __builtin_amdgcn_s_barrier();
    __builtin_amdgcn_s_setprio(1);
#pragma unroll
    for (int m = 0; m < 4; ++m)
#pragma unroll
      for (int n = 0; n < 4; ++n)
        acc[m + 4][n] = __builtin_amdgcn_mfma_f32_16x16x32_bf16(a1[m], b0[n], acc[m + 4][n], 0, 0, 0);
    __builtin_amdgcn_s_setprio(0);

    // ---- phase 2: B(ks1) + A-low(ks1) ----
    bf16x8 b1[4], a2[4];
#pragma unroll
    for (int n = 0; n < 4; ++n)
      b1[n] = *(const bf16x8*)(bs + (wc * 64 + n * 16 + row16) * BK + cb1);
#pragma unroll
    for (int m = 0; m < 4; ++m)
      a2[m] = *(const bf16x8*)(as + (wr * 128 + m * 16 + row16) * BK + cb1);
    __builtin_amdgcn_sched_barrier(0);
    __builtin_amdgcn_s_barrier();
    __builtin_amdgcn_s_setprio(1);
#pragma unroll
    for (int m = 0; m < 4; ++m)
#pragma unroll
      for (int n = 0; n < 4; ++n)
        acc[m][n] = __builtin_amdgcn_mfma_f32_16x16x32_bf16(a2[m], b1[n], acc[m][n], 0, 0, 0);
    __builtin_amdgcn_s_setprio(0);

    // ---- phase 3: A-high(ks1) ----
    bf16x8 a3[4];
#pragma unroll
    for (int m = 0; m < 4; ++m)
      a3[m] = *(const bf16x8*)(as + (wr * 128 + (m + 4) * 16 + row16) * BK + cb1);
    __builtin_amdgcn_sched_barrier(0);
    __builtin_amdgcn_s_barrier();
    __builtin_amdgcn_s_setprio(1);
#pragma unroll
    for (int m = 0; m < 4; ++m)
#pragma unroll
      for (int n = 0; n < 4; ++n)
        acc[m + 4][n] = __builtin_amdgcn_mfma_f32_16x16x32_bf16(a3[m], b1[n], acc[m + 4][n], 0, 0, 0);
    __builtin_amdgcn_s_setprio(0);

    consA = (consA == 2) ? 0 : consA + 1;
  }

  if (s == 3) {
    float* Cb = C + (size_t)(m0 + wr * 128) * OUT_F + n0 + wc * 64;
#pragma unroll
    for (int m = 0; m < 8; ++m)
#pragma unroll
      for (int n = 0; n < 4; ++n)
#pragma unroll
        for (int r = 0; r < 4; ++r)
          Cb[(size_t)(m * 16 + kgrp * 4 + r) * OUT_F + n * 16 + row16] = acc[m][n][r];
  } else {
    unsigned short* Pb = P + (size_t)s * BATCHN * OUT_F
                       + (size_t)(m0 + wr * 128) * OUT_F + n0 + wc * 64;
#pragma unroll
    for (int m = 0; m < 8; ++m)
#pragma unroll
      for (int n = 0; n < 4; ++n)
#pragma unroll
        for (int r = 0; r < 4; ++r)
          Pb[(size_t)(m * 16 + kgrp * 4 + r) * OUT_F + n * 16 + row16] = f2bf(acc[m][n][r]);
  }
}

// ---------------------------------------------------------------------------
// Merge split-K partials (3x bf16) + LayerNorm over last dim (1024), in-place.
// ---------------------------------------------------------------------------
__global__ __launch_bounds__(256) void kan_ln(float* __restrict__ y,
                                              const unsigned short* __restrict__ P,
                                              const float* __restrict__ gamma,
                                              const float* __restrict__ beta) {
  __shared__ float ss[4], ssq[4];
  int tid = threadIdx.x;
  float4* p = (float4*)(y + (size_t)blockIdx.x * OUT_F);
  float4 v = p[tid];
#pragma unroll
  for (int pp = 0; pp < 3; ++pp) {
    const ushort4 pv = ((const ushort4*)(P + (size_t)pp * BATCHN * OUT_F
                                           + (size_t)blockIdx.x * OUT_F))[tid];
    v.x += bf2f(pv.x);
    v.y += bf2f(pv.y);
    v.z += bf2f(pv.z);
    v.w += bf2f(pv.w);
  }
  float s = v.x + v.y + v.z + v.w;
  float q = v.x * v.x + v.y * v.y + v.z * v.z + v.w * v.w;
#pragma unroll
  for (int off = 1; off < 64; off <<= 1) {
    s += __shfl_xor(s, off);
    q += __shfl_xor(q, off);
  }
  if ((tid & 63) == 0) { ss[tid >> 6] = s; ssq[tid >> 6] = q; }
  __syncthreads();
  float S = ss[0] + ss[1] + ss[2] + ss[3];
  float Q = ssq[0] + ssq[1] + ssq[2] + ssq[3];
  float mu  = S * (1.0f / OUT_F);
  float var = Q * (1.0f / OUT_F) - mu * mu;
  float inv = rsqrtf(var + 1e-5f);
  const float4 g  = ((const float4*)gamma)[tid];
  const float4 bt = ((const float4*)beta)[tid];
  float4 o;
  o.x = (v.x - mu) * inv * g.x + bt.x;
  o.y = (v.y - mu) * inv * g.y + bt.y;
  o.z = (v.z - mu) * inv * g.z + bt.z;
  o.w = (v.w - mu) * inv * g.w + bt.w;
  p[tid] = o;
}

extern "C" void kernel_launch(void* const* d_in, const int* in_sizes, int n_in,
                              void* d_out, int out_size, void* d_ws, size_t ws_size,
                              hipStream_t stream) {
  const float* x     = (const float*)d_in[0];
  const float* coef  = (const float*)d_in[1];
  const float* sb    = (const float*)d_in[2];
  const float* ssp   = (const float*)d_in[3];
  const float* gamma = (const float*)d_in[4];
  const float* beta  = (const float*)d_in[5];
  const float* grid  = (const float*)d_in[6];

  const size_t a_elems  = (size_t)BATCHN * KDIM;       // 75.5 MB bf16
  const size_t wt_elems = (size_t)OUT_F * KDIM;        // 18.9 MB bf16
  const size_t p_elems  = (size_t)3 * BATCHN * OUT_F;  // 25.2 MB bf16
  if (ws_size < (a_elems + wt_elems + p_elems) * sizeof(unsigned short)) return;

  unsigned short* A  = (unsigned short*)d_ws;
  unsigned short* WT = A + a_elems;
  unsigned short* P  = WT + wt_elems;
  float* y = (float*)d_out;

  const size_t lds_bytes = (3 * (size_t)A_SLOT + 2 * (size_t)B_SLOT) * sizeof(unsigned short); // 160 KiB
  static bool attr_set = false;
  if (!attr_set) {
    hipFuncSetAttribute((const void*)kan_gemm,
                        hipFuncAttributeMaxDynamicSharedMemorySize, (int)lds_bytes);
    attr_set = true;
  }

  kan_prep_a<<<dim3((BATCHN * IN_F) / 256), dim3(256), 0, stream>>>(x, grid, A);
  kan_prep_w<<<dim3((IN_F / 32) * (OUT_F / 32)), dim3(256), 0, stream>>>(sb, ssp, coef, WT);
  kan_gemm<<<dim3(4 * (BATCHN / BM) * (OUT_F / BN)), dim3(512), lds_bytes, stream>>>(A, WT, y, P);
  kan_ln<<<dim3(BATCHN), dim3(256), 0, stream>>>(y, P, gamma, beta);
}